// Round 4
// baseline (128.634 us; speedup 1.0000x reference)
//
#include <hip/hip_runtime.h>

// Problem: N=8 prior blocks, B=4, C=256, H=W=64.
// V = concat(blocks, x) -> [9,4,256,64,64]
// GroupNorm(1 group) over (C,H,W) per (n,b); logits = <w, K> over c;
// softmax over n; out = sum_n attn * V.
//
// Key identity: logits = rstd*(S - mean*sum_wg) + sum_wgb
//   where S[n,b,hw] = sum_c (w[c]*gnw[c]) * V[n,b,c,hw]
//         sum_wg = sum_c w[c]*gnw[c],  sum_wgb = sum_c w[c]*gnb[c]
//
// Two passes over V:
//   k1: stats (sum, sumsq) partials + channel-dot partials S_part
//   k2: per-(b, 8-hw strip) block: reduce stats, compute softmax over n
//       in-block, then out = sum_n attn * V across all 256 c.

#define NPRI 8
#define N1   9
#define BB   4
#define CC   256
#define HWN  4096
#define CHW  (CC * HWN)          // 1048576
#define NB   (N1 * BB)           // 36
#define GN_EPS 1e-5f

// workspace layout (floats):
//   [0..2303]      psum[36][64]   per-(nb, cq*16+hwseg) partial sum
//   [2304..4607]   psq [36][64]   partial sum-of-squares
//   [4608..)       S_part[4][36][4096] = 589824 floats (16B-aligned)
#define WS_PSUM   0
#define WS_PSQ    2304
#define WS_SPART  4608

// ---------------- kernel 1: stats + channel-dot partials ----------------
// grid = 36 (nb) * 4 (cq) * 16 (hwseg) = 2304 blocks (9 per CU),
// 256 threads = 4 c-groups (16 ch each) x 64 lanes (64 float4 = 256 floats).
__global__ __launch_bounds__(256, 4) void k1_stats(
        const float* __restrict__ blocks, const float* __restrict__ x,
        const float* __restrict__ w, const float* __restrict__ gnw,
        float* __restrict__ ws) {
    const int bid   = blockIdx.x;
    const int nb    = bid >> 6;          // 0..35
    const int rem   = bid & 63;
    const int cq    = rem >> 4;          // 0..3
    const int hwseg = rem & 15;          // 0..15
    const int t     = threadIdx.x;
    const int cg    = t >> 6;            // 0..3
    const int lane  = t & 63;

    const float* base = (nb < NPRI * BB)
        ? blocks + (size_t)nb * CHW
        : x + (size_t)(nb - NPRI * BB) * CHW;

    const int hw0 = hwseg * 256 + lane * 4;
    const int c0  = cq * 64 + cg * 16;

    float s0 = 0.f, s1 = 0.f, s2 = 0.f, s3 = 0.f;   // channel-dot partial
    float sum = 0.f, sq = 0.f;

    #pragma unroll 4
    for (int c = c0; c < c0 + 16; ++c) {
        const float4 v = *reinterpret_cast<const float4*>(base + (size_t)c * HWN + hw0);
        const float wg = w[c] * gnw[c];
        sum += v.x + v.y + v.z + v.w;
        sq  += v.x * v.x + v.y * v.y + v.z * v.z + v.w * v.w;
        s0 += wg * v.x; s1 += wg * v.y; s2 += wg * v.z; s3 += wg * v.w;
    }

    // combine 4 c-groups' channel-dot via LDS; cg0 writes final cq-partial
    __shared__ float4 sbuf[3][64];
    if (cg) sbuf[cg - 1][lane] = make_float4(s0, s1, s2, s3);
    __syncthreads();
    if (!cg) {
        #pragma unroll
        for (int g = 0; g < 3; ++g) {
            const float4 o = sbuf[g][lane];
            s0 += o.x; s1 += o.y; s2 += o.z; s3 += o.w;
        }
        float* Sp = ws + WS_SPART;
        *reinterpret_cast<float4*>(Sp + (size_t)(cq * NB + nb) * HWN + hw0) =
            make_float4(s0, s1, s2, s3);
    }

    // block-reduce sum/sq -> unique slot (no atomics)
    #pragma unroll
    for (int off = 32; off; off >>= 1) {
        sum += __shfl_down(sum, off);
        sq  += __shfl_down(sq, off);
    }
    __shared__ float red[8];
    if (lane == 0) { red[cg] = sum; red[4 + cg] = sq; }
    __syncthreads();
    if (t == 0) {
        const int slot = nb * 64 + rem;
        ws[WS_PSUM + slot] = red[0] + red[1] + red[2] + red[3];
        ws[WS_PSQ  + slot] = red[4] + red[5] + red[6] + red[7];
    }
}

// -------- kernel 2: fused stats-finalize + softmax + weighted sum --------
// grid = B(4) * 512 hw-strips = 2048 blocks (8 per CU), 256 threads.
// Block owns (b, hw0..hw0+7) for ALL 256 channels, all 9 n.
// Thread map: hw4 = t&1 (which float4 of the strip), c = t>>1 (0..127),
// second c-half at c+128.
__global__ __launch_bounds__(256, 4) void k2_fused(
        const float* __restrict__ blocks, const float* __restrict__ x,
        const float* __restrict__ w, const float* __restrict__ gnw,
        const float* __restrict__ gnb,
        const float* __restrict__ ws, float* __restrict__ out) {
    const int bid = blockIdx.x;
    const int b   = bid >> 9;            // 0..3
    const int hw0 = (bid & 511) * 8;
    const int t   = threadIdx.x;

    __shared__ float red[8];
    __shared__ float swg_s, swgb_s;
    __shared__ float mean_s[NB], rstd_s[NB];
    __shared__ float logit_s[N1][8];
    __shared__ float4 attn4_s[N1][2];

    // ---- swg = <w,gnw>, swgb = <w,gnb> (block reduce, C==256) ----
    {
        float p = w[t] * gnw[t];
        float q = w[t] * gnb[t];
        #pragma unroll
        for (int off = 32; off; off >>= 1) {
            p += __shfl_down(p, off);
            q += __shfl_down(q, off);
        }
        const int wave = t >> 6, lane = t & 63;
        if (lane == 0) { red[wave] = p; red[4 + wave] = q; }
    }

    // ---- stats: threads 0..35 reduce 64 partials for one nb ----
    if (t < NB) {
        float s = 0.f, ss = 0.f;
        #pragma unroll 8
        for (int i = 0; i < 64; ++i) {
            s  += ws[WS_PSUM + t * 64 + i];
            ss += ws[WS_PSQ  + t * 64 + i];
        }
        const float mean = s * (1.0f / CHW);
        const float var  = ss * (1.0f / CHW) - mean * mean;
        mean_s[t] = mean;
        rstd_s[t] = rsqrtf(var + GN_EPS);
    }
    __syncthreads();
    if (t == 0) {
        swg_s  = red[0] + red[1] + red[2] + red[3];
        swgb_s = red[4] + red[5] + red[6] + red[7];
    }
    __syncthreads();

    // ---- logits for the 8 hw of this strip, all 9 n ----
    if (t < N1 * 8) {
        const int n   = t >> 3;
        const int hwi = t & 7;
        const int nb  = n * BB + b;
        const float* Sp = ws + WS_SPART;
        const size_t o = (size_t)nb * HWN + hw0 + hwi;
        const float S = Sp[o] + Sp[(size_t)NB * HWN + o]
                      + Sp[(size_t)2 * NB * HWN + o] + Sp[(size_t)3 * NB * HWN + o];
        logit_s[n][hwi] = rstd_s[nb] * (S - mean_s[nb] * swg_s) + swgb_s;
    }
    __syncthreads();

    // ---- softmax over n for each hw (8 threads) ----
    if (t < 8) {
        float mx = -1e30f;
        #pragma unroll
        for (int n = 0; n < N1; ++n) mx = fmaxf(mx, logit_s[n][t]);
        float den = 0.f;
        float e[N1];
        #pragma unroll
        for (int n = 0; n < N1; ++n) { e[n] = __expf(logit_s[n][t] - mx); den += e[n]; }
        const float inv = 1.0f / den;
        float* attn_f = (float*)attn4_s;   // [n][8] row-major
        #pragma unroll
        for (int n = 0; n < N1; ++n) attn_f[n * 8 + t] = e[n] * inv;
    }
    __syncthreads();

    // ---- weighted sum over n for all 256 c ----
    const int hw4 = t & 1;               // which float4 of the 8-hw strip
    const int c_  = t >> 1;              // 0..127 ; also handles c_+128
    const int hw  = hw0 + hw4 * 4;

    float4 acc0 = make_float4(0.f, 0.f, 0.f, 0.f);
    float4 acc1 = make_float4(0.f, 0.f, 0.f, 0.f);

    #pragma unroll
    for (int n = 0; n < N1; ++n) {
        const float* vb = (n < NPRI)
            ? blocks + (size_t)(n * BB + b) * CHW
            : x + (size_t)b * CHW;
        const float4 a  = attn4_s[n][hw4];
        const float4 v0 = *reinterpret_cast<const float4*>(vb + (size_t)c_ * HWN + hw);
        const float4 v1 = *reinterpret_cast<const float4*>(vb + (size_t)(c_ + 128) * HWN + hw);
        acc0.x += a.x * v0.x; acc0.y += a.y * v0.y; acc0.z += a.z * v0.z; acc0.w += a.w * v0.w;
        acc1.x += a.x * v1.x; acc1.y += a.y * v1.y; acc1.z += a.z * v1.z; acc1.w += a.w * v1.w;
    }

    float* o0 = out + (size_t)(b * CC + c_) * HWN + hw;
    float* o1 = out + (size_t)(b * CC + c_ + 128) * HWN + hw;
    __builtin_nontemporal_store(acc0.x, o0 + 0);
    __builtin_nontemporal_store(acc0.y, o0 + 1);
    __builtin_nontemporal_store(acc0.z, o0 + 2);
    __builtin_nontemporal_store(acc0.w, o0 + 3);
    __builtin_nontemporal_store(acc1.x, o1 + 0);
    __builtin_nontemporal_store(acc1.y, o1 + 1);
    __builtin_nontemporal_store(acc1.z, o1 + 2);
    __builtin_nontemporal_store(acc1.w, o1 + 3);
}

extern "C" void kernel_launch(void* const* d_in, const int* in_sizes, int n_in,
                              void* d_out, int out_size, void* d_ws, size_t ws_size,
                              hipStream_t stream) {
    const float* blocks = (const float*)d_in[0];
    const float* x      = (const float*)d_in[1];
    const float* w      = (const float*)d_in[2];
    const float* gnw    = (const float*)d_in[3];
    const float* gnb    = (const float*)d_in[4];
    float* out = (float*)d_out;
    float* ws  = (float*)d_ws;

    hipLaunchKernelGGL(k1_stats, dim3(2304), dim3(256), 0, stream, blocks, x, w, gnw, ws);
    hipLaunchKernelGGL(k2_fused, dim3(2048), dim3(256), 0, stream,
                       blocks, x, w, gnw, gnb, ws, out);
}

// Round 5
// 77.305 us; speedup vs baseline: 1.6640x; 1.6640x over previous
//
#include <hip/hip_runtime.h>

// Problem: N=8 prior blocks, B=4, C=256, H=W=64.
// V = concat(blocks, x) -> [9,4,256,64,64]
// GroupNorm(1 group) over (C,H,W) per (n,b); logits = <w, K> over c;
// softmax over n; out = sum_n attn * V.
//
// Key identity: logits = rstd*(S - mean*sum_wg) + sum_wgb
//   where S[n,b,hw] = sum_c (w[c]*gnw[c]) * V[n,b,c,hw]
//         sum_wg = sum_c w[c]*gnw[c],  sum_wgb = sum_c w[c]*gnb[c]
//
// Two passes over V:
//   k1: stats (sum, sumsq) partials + channel-dot partials S_part
//   k2: per-(b, 16-hw strip) block: reduce stats, softmax over n in-block,
//       then out = sum_n attn * V across all 256 c.
//       Strip = 16 hw = 64 B per channel row = one fetch granule (round-4
//       lesson: 8-hw strips = 32 B caused exactly 2x HBM over-fetch).

#define NPRI 8
#define N1   9
#define BB   4
#define CC   256
#define HWN  4096
#define CHW  (CC * HWN)          // 1048576
#define NB   (N1 * BB)           // 36
#define GN_EPS 1e-5f

// workspace layout (floats):
//   [0..2303]      psum[36][64]   per-(nb, cq*16+hwseg) partial sum
//   [2304..4607]   psq [36][64]   partial sum-of-squares
//   [4608..)       S_part[4][36][4096] = 589824 floats (16B-aligned)
#define WS_PSUM   0
#define WS_PSQ    2304
#define WS_SPART  4608

// ---------------- kernel 1: stats + channel-dot partials ----------------
// grid = 36 (nb) * 4 (cq) * 16 (hwseg) = 2304 blocks (9 per CU),
// 256 threads = 4 c-groups (16 ch each) x 64 lanes (64 float4 = 256 floats).
__global__ __launch_bounds__(256, 4) void k1_stats(
        const float* __restrict__ blocks, const float* __restrict__ x,
        const float* __restrict__ w, const float* __restrict__ gnw,
        float* __restrict__ ws) {
    const int bid   = blockIdx.x;
    const int nb    = bid >> 6;          // 0..35
    const int rem   = bid & 63;
    const int cq    = rem >> 4;          // 0..3
    const int hwseg = rem & 15;          // 0..15
    const int t     = threadIdx.x;
    const int cg    = t >> 6;            // 0..3
    const int lane  = t & 63;

    const float* base = (nb < NPRI * BB)
        ? blocks + (size_t)nb * CHW
        : x + (size_t)(nb - NPRI * BB) * CHW;

    const int hw0 = hwseg * 256 + lane * 4;
    const int c0  = cq * 64 + cg * 16;

    float s0 = 0.f, s1 = 0.f, s2 = 0.f, s3 = 0.f;   // channel-dot partial
    float sum = 0.f, sq = 0.f;

    #pragma unroll 4
    for (int c = c0; c < c0 + 16; ++c) {
        const float4 v = *reinterpret_cast<const float4*>(base + (size_t)c * HWN + hw0);
        const float wg = w[c] * gnw[c];
        sum += v.x + v.y + v.z + v.w;
        sq  += v.x * v.x + v.y * v.y + v.z * v.z + v.w * v.w;
        s0 += wg * v.x; s1 += wg * v.y; s2 += wg * v.z; s3 += wg * v.w;
    }

    // combine 4 c-groups' channel-dot via LDS; cg0 writes final cq-partial
    __shared__ float4 sbuf[3][64];
    if (cg) sbuf[cg - 1][lane] = make_float4(s0, s1, s2, s3);
    __syncthreads();
    if (!cg) {
        #pragma unroll
        for (int g = 0; g < 3; ++g) {
            const float4 o = sbuf[g][lane];
            s0 += o.x; s1 += o.y; s2 += o.z; s3 += o.w;
        }
        float* Sp = ws + WS_SPART;
        *reinterpret_cast<float4*>(Sp + (size_t)(cq * NB + nb) * HWN + hw0) =
            make_float4(s0, s1, s2, s3);
    }

    // block-reduce sum/sq -> unique slot (no atomics)
    #pragma unroll
    for (int off = 32; off; off >>= 1) {
        sum += __shfl_down(sum, off);
        sq  += __shfl_down(sq, off);
    }
    __shared__ float red[8];
    if (lane == 0) { red[cg] = sum; red[4 + cg] = sq; }
    __syncthreads();
    if (t == 0) {
        const int slot = nb * 64 + rem;
        ws[WS_PSUM + slot] = red[0] + red[1] + red[2] + red[3];
        ws[WS_PSQ  + slot] = red[4] + red[5] + red[6] + red[7];
    }
}

// -------- kernel 2: fused stats-finalize + softmax + weighted sum --------
// grid = B(4) * 256 strips = 1024 blocks (4 per CU), 256 threads.
// Block owns (b, hw0..hw0+15) for ALL 256 channels, all 9 n.
// Main loop map: hwq = t&3 (which float4 of the 16-hw strip),
// c_ = t>>2 (0..63), c-chunks at c_ + 64k, k=0..3.
__global__ __launch_bounds__(256, 4) void k2_fused(
        const float* __restrict__ blocks, const float* __restrict__ x,
        const float* __restrict__ w, const float* __restrict__ gnw,
        const float* __restrict__ gnb,
        const float* __restrict__ ws, float* __restrict__ out) {
    const int bid = blockIdx.x;
    const int b   = bid >> 8;            // 0..3
    const int hw0 = (bid & 255) * 16;
    const int t   = threadIdx.x;

    __shared__ float red[8];
    __shared__ float swg_s, swgb_s;
    __shared__ float mean_s[NB], rstd_s[NB];
    __shared__ float logit_s[N1][16];
    __shared__ float4 attn4_s[N1][4];

    // ---- swg = <w,gnw>, swgb = <w,gnb> (block reduce, C==256) ----
    {
        float p = w[t] * gnw[t];
        float q = w[t] * gnb[t];
        #pragma unroll
        for (int off = 32; off; off >>= 1) {
            p += __shfl_down(p, off);
            q += __shfl_down(q, off);
        }
        const int wave = t >> 6, lane = t & 63;
        if (lane == 0) { red[wave] = p; red[4 + wave] = q; }
    }

    // ---- stats: threads 0..35 reduce 64 partials for one nb ----
    if (t < NB) {
        float s = 0.f, ss = 0.f;
        #pragma unroll 8
        for (int i = 0; i < 64; ++i) {
            s  += ws[WS_PSUM + t * 64 + i];
            ss += ws[WS_PSQ  + t * 64 + i];
        }
        const float mean = s * (1.0f / CHW);
        const float var  = ss * (1.0f / CHW) - mean * mean;
        mean_s[t] = mean;
        rstd_s[t] = rsqrtf(var + GN_EPS);
    }
    __syncthreads();
    if (t == 0) {
        swg_s  = red[0] + red[1] + red[2] + red[3];
        swgb_s = red[4] + red[5] + red[6] + red[7];
    }
    __syncthreads();

    // ---- logits for the 16 hw of this strip, all 9 n (144 threads) ----
    if (t < N1 * 16) {
        const int n   = t >> 4;
        const int hwi = t & 15;
        const int nb  = n * BB + b;
        const float* Sp = ws + WS_SPART;
        const size_t o = (size_t)nb * HWN + hw0 + hwi;
        const float S = Sp[o] + Sp[(size_t)NB * HWN + o]
                      + Sp[(size_t)2 * NB * HWN + o] + Sp[(size_t)3 * NB * HWN + o];
        logit_s[n][hwi] = rstd_s[nb] * (S - mean_s[nb] * swg_s) + swgb_s;
    }
    __syncthreads();

    // ---- softmax over n for each hw (16 threads) ----
    if (t < 16) {
        float mx = -1e30f;
        #pragma unroll
        for (int n = 0; n < N1; ++n) mx = fmaxf(mx, logit_s[n][t]);
        float den = 0.f;
        float e[N1];
        #pragma unroll
        for (int n = 0; n < N1; ++n) { e[n] = __expf(logit_s[n][t] - mx); den += e[n]; }
        const float inv = 1.0f / den;
        float* attn_f = (float*)attn4_s;   // [n][16] row-major
        #pragma unroll
        for (int n = 0; n < N1; ++n) attn_f[n * 16 + t] = e[n] * inv;
    }
    __syncthreads();

    // ---- weighted sum over n for all 256 c ----
    const int hwq = t & 3;               // which float4 of the 16-hw strip
    const int c_  = t >> 2;              // 0..63 ; chunks at c_ + 64k
    const int hw  = hw0 + hwq * 4;

    float4 acc[4];
    #pragma unroll
    for (int k = 0; k < 4; ++k) acc[k] = make_float4(0.f, 0.f, 0.f, 0.f);

    #pragma unroll
    for (int n = 0; n < N1; ++n) {
        const float* vb = (n < NPRI)
            ? blocks + (size_t)(n * BB + b) * CHW
            : x + (size_t)b * CHW;
        const float4 a = attn4_s[n][hwq];
        #pragma unroll
        for (int k = 0; k < 4; ++k) {
            const float4 v = *reinterpret_cast<const float4*>(
                vb + (size_t)(c_ + 64 * k) * HWN + hw);
            acc[k].x += a.x * v.x; acc[k].y += a.y * v.y;
            acc[k].z += a.z * v.z; acc[k].w += a.w * v.w;
        }
    }

    #pragma unroll
    for (int k = 0; k < 4; ++k) {
        float* o = out + (size_t)(b * CC + c_ + 64 * k) * HWN + hw;
        __builtin_nontemporal_store(acc[k].x, o + 0);
        __builtin_nontemporal_store(acc[k].y, o + 1);
        __builtin_nontemporal_store(acc[k].z, o + 2);
        __builtin_nontemporal_store(acc[k].w, o + 3);
    }
}

extern "C" void kernel_launch(void* const* d_in, const int* in_sizes, int n_in,
                              void* d_out, int out_size, void* d_ws, size_t ws_size,
                              hipStream_t stream) {
    const float* blocks = (const float*)d_in[0];
    const float* x      = (const float*)d_in[1];
    const float* w      = (const float*)d_in[2];
    const float* gnw    = (const float*)d_in[3];
    const float* gnb    = (const float*)d_in[4];
    float* out = (float*)d_out;
    float* ws  = (float*)d_ws;

    hipLaunchKernelGGL(k1_stats, dim3(2304), dim3(256), 0, stream, blocks, x, w, gnw, ws);
    hipLaunchKernelGGL(k2_fused, dim3(1024), dim3(256), 0, stream,
                       blocks, x, w, gnw, gnb, ws, out);
}

// Round 6
// 57.085 us; speedup vs baseline: 2.2534x; 1.3542x over previous
//
#include <hip/hip_runtime.h>

// Problem: N=8 prior blocks, B=4, C=256, H=W=64.
// V = concat(blocks, x) -> [9,4,256,64,64]
// GroupNorm(1 group) over (C,H,W) per (n,b); logits = <w, K> over c;
// softmax over n; out = sum_n attn * V.
//
// Key identity: logits = rstd*(S - mean*sum_wg) + sum_wgb
//   where S[n,b,hw] = sum_c (w[c]*gnw[c]) * V[n,b,c,hw]
//
// Two passes over V:
//   k1: stats (sum,sumsq) partials + channel-dot partials S_part.
//   k2: block = (b, 256-hw segment, 16-c chunk). Prologue: reduce stats +
//       logits + softmax for the segment (L2-resident, redundant across
//       c-chunks). Main loop: wave streams 1KB-contiguous (n,c) rows.
//       (round-5 lesson: 64B scattered granules -> 3.3 TB/s; need >=1KB
//       contiguous per wave like round-3's k3 which hit 6.3 TB/s.)

#define NPRI 8
#define N1   9
#define BB   4
#define CC   256
#define HWN  4096
#define CHW  (CC * HWN)          // 1048576
#define NB   (N1 * BB)           // 36
#define GN_EPS 1e-5f

// workspace layout (floats):
//   [0..2303]      psum[36][64]
//   [2304..4607]   psq [36][64]
//   [4608..)       S_part[4][36][4096] = 589824 floats
#define WS_PSUM   0
#define WS_PSQ    2304
#define WS_SPART  4608

// ---------------- kernel 1: stats + channel-dot partials ----------------
// grid = 36 (nb) * 4 (cq) * 16 (hwseg) = 2304 blocks (9 per CU),
// 256 threads = 4 c-groups (16 ch each) x 64 lanes (64 float4 = 256 floats).
__global__ __launch_bounds__(256, 4) void k1_stats(
        const float* __restrict__ blocks, const float* __restrict__ x,
        const float* __restrict__ w, const float* __restrict__ gnw,
        float* __restrict__ ws) {
    const int bid   = blockIdx.x;
    const int nb    = bid >> 6;          // 0..35
    const int rem   = bid & 63;
    const int cq    = rem >> 4;          // 0..3
    const int hwseg = rem & 15;          // 0..15
    const int t     = threadIdx.x;
    const int cg    = t >> 6;            // 0..3
    const int lane  = t & 63;

    const float* base = (nb < NPRI * BB)
        ? blocks + (size_t)nb * CHW
        : x + (size_t)(nb - NPRI * BB) * CHW;

    const int hw0 = hwseg * 256 + lane * 4;
    const int c0  = cq * 64 + cg * 16;

    float s0 = 0.f, s1 = 0.f, s2 = 0.f, s3 = 0.f;   // channel-dot partial
    float sum = 0.f, sq = 0.f;

    #pragma unroll 4
    for (int c = c0; c < c0 + 16; ++c) {
        const float4 v = *reinterpret_cast<const float4*>(base + (size_t)c * HWN + hw0);
        const float wg = w[c] * gnw[c];
        sum += v.x + v.y + v.z + v.w;
        sq  += v.x * v.x + v.y * v.y + v.z * v.z + v.w * v.w;
        s0 += wg * v.x; s1 += wg * v.y; s2 += wg * v.z; s3 += wg * v.w;
    }

    // combine 4 c-groups' channel-dot via LDS; cg0 writes final cq-partial
    __shared__ float4 sbuf[3][64];
    if (cg) sbuf[cg - 1][lane] = make_float4(s0, s1, s2, s3);
    __syncthreads();
    if (!cg) {
        #pragma unroll
        for (int g = 0; g < 3; ++g) {
            const float4 o = sbuf[g][lane];
            s0 += o.x; s1 += o.y; s2 += o.z; s3 += o.w;
        }
        float* Sp = ws + WS_SPART;
        *reinterpret_cast<float4*>(Sp + (size_t)(cq * NB + nb) * HWN + hw0) =
            make_float4(s0, s1, s2, s3);
    }

    // block-reduce sum/sq -> unique slot (no atomics)
    #pragma unroll
    for (int off = 32; off; off >>= 1) {
        sum += __shfl_down(sum, off);
        sq  += __shfl_down(sq, off);
    }
    __shared__ float red[8];
    if (lane == 0) { red[cg] = sum; red[4 + cg] = sq; }
    __syncthreads();
    if (t == 0) {
        const int slot = nb * 64 + rem;
        ws[WS_PSUM + slot] = red[0] + red[1] + red[2] + red[3];
        ws[WS_PSQ  + slot] = red[4] + red[5] + red[6] + red[7];
    }
}

// -------- kernel 2: fused stats-finalize + softmax + weighted sum --------
// grid = 4 (b) * 16 (hwseg of 256 hw) * 16 (c-chunk of 16) = 1024 blocks
// (4 per CU), 256 threads = 4 waves.
__global__ __launch_bounds__(256, 4) void k2_fused(
        const float* __restrict__ blocks, const float* __restrict__ x,
        const float* __restrict__ w, const float* __restrict__ gnw,
        const float* __restrict__ gnb,
        const float* __restrict__ ws, float* __restrict__ out) {
    const int bid   = blockIdx.x;
    const int b     = bid >> 8;          // 0..3
    const int hwseg = (bid >> 4) & 15;   // 0..15
    const int cch   = bid & 15;          // 0..15
    const int t     = threadIdx.x;
    const int wv    = t >> 6, lane = t & 63;

    __shared__ float red[8];
    __shared__ float swg_s, swgb_s;
    __shared__ float mean_s[NB], rstd_s[NB];
    __shared__ float attn_s[N1][256];    // logits, then attn (in place)

    // ---- swg = <w,gnw>, swgb = <w,gnb> (block reduce, C==256) ----
    {
        float p = w[t] * gnw[t];
        float q = w[t] * gnb[t];
        #pragma unroll
        for (int off = 32; off; off >>= 1) {
            p += __shfl_down(p, off);
            q += __shfl_down(q, off);
        }
        if (lane == 0) { red[wv] = p; red[4 + wv] = q; }
    }

    // ---- stats: threads 0..35 reduce 64 partials for one nb ----
    if (t < NB) {
        float s = 0.f, ss = 0.f;
        #pragma unroll 8
        for (int i = 0; i < 64; ++i) {
            s  += ws[WS_PSUM + t * 64 + i];
            ss += ws[WS_PSQ  + t * 64 + i];
        }
        const float mean = s * (1.0f / CHW);
        const float var  = ss * (1.0f / CHW) - mean * mean;
        mean_s[t] = mean;
        rstd_s[t] = rsqrtf(var + GN_EPS);
    }
    __syncthreads();
    if (t == 0) {
        swg_s  = red[0] + red[1] + red[2] + red[3];
        swgb_s = red[4] + red[5] + red[6] + red[7];
    }
    __syncthreads();

    // ---- logits for this 256-hw segment, all 9 n (coalesced 1KB rows) ----
    const int hwbase = hwseg * 256;
    {
        const float* Sp = ws + WS_SPART;
        const float swg = swg_s, swgb = swgb_s;
        #pragma unroll
        for (int n = 0; n < N1; ++n) {
            const int nb = n * BB + b;
            const size_t o = (size_t)nb * HWN + hwbase + t;
            const float S = Sp[o] + Sp[(size_t)NB * HWN + o]
                          + Sp[(size_t)2 * NB * HWN + o] + Sp[(size_t)3 * NB * HWN + o];
            attn_s[n][t] = rstd_s[nb] * (S - mean_s[nb] * swg) + swgb;
        }
    }
    __syncthreads();

    // ---- softmax over n, thread t owns hw column t, in place ----
    {
        float l[N1];
        float mx = -1e30f;
        #pragma unroll
        for (int n = 0; n < N1; ++n) { l[n] = attn_s[n][t]; mx = fmaxf(mx, l[n]); }
        float den = 0.f;
        #pragma unroll
        for (int n = 0; n < N1; ++n) { l[n] = __expf(l[n] - mx); den += l[n]; }
        const float inv = 1.0f / den;
        #pragma unroll
        for (int n = 0; n < N1; ++n) attn_s[n][t] = l[n] * inv;
    }
    __syncthreads();

    // ---- weighted sum over n: wave wv streams (n, c) rows of 1KB ----
    // wave wv handles c_local = wv + 4k (k=0..3); lane covers hw = lane*4.
    const int c0 = cch * 16;
    const int hw = hwbase + lane * 4;

    float4 acc[4];
    #pragma unroll
    for (int k = 0; k < 4; ++k) acc[k] = make_float4(0.f, 0.f, 0.f, 0.f);

    #pragma unroll
    for (int n = 0; n < N1; ++n) {
        const float* vb = (n < NPRI)
            ? blocks + (size_t)(n * BB + b) * CHW
            : x + (size_t)b * CHW;
        const float4 a = *reinterpret_cast<const float4*>(&attn_s[n][lane * 4]);
        #pragma unroll
        for (int k = 0; k < 4; ++k) {
            const int c = c0 + wv + 4 * k;
            const float4 v = *reinterpret_cast<const float4*>(
                vb + (size_t)c * HWN + hw);
            acc[k].x += a.x * v.x; acc[k].y += a.y * v.y;
            acc[k].z += a.z * v.z; acc[k].w += a.w * v.w;
        }
    }

    #pragma unroll
    for (int k = 0; k < 4; ++k) {
        const int c = c0 + wv + 4 * k;
        float* o = out + (size_t)(b * CC + c) * HWN + hw;
        __builtin_nontemporal_store(acc[k].x, o + 0);
        __builtin_nontemporal_store(acc[k].y, o + 1);
        __builtin_nontemporal_store(acc[k].z, o + 2);
        __builtin_nontemporal_store(acc[k].w, o + 3);
    }
}

extern "C" void kernel_launch(void* const* d_in, const int* in_sizes, int n_in,
                              void* d_out, int out_size, void* d_ws, size_t ws_size,
                              hipStream_t stream) {
    const float* blocks = (const float*)d_in[0];
    const float* x      = (const float*)d_in[1];
    const float* w      = (const float*)d_in[2];
    const float* gnw    = (const float*)d_in[3];
    const float* gnb    = (const float*)d_in[4];
    float* out = (float*)d_out;
    float* ws  = (float*)d_ws;

    hipLaunchKernelGGL(k1_stats, dim3(2304), dim3(256), 0, stream, blocks, x, w, gnw, ws);
    hipLaunchKernelGGL(k2_fused, dim3(1024), dim3(256), 0, stream,
                       blocks, x, w, gnw, gnb, ws, out);
}

// Round 7
// 53.979 us; speedup vs baseline: 2.3830x; 1.0575x over previous
//
#include <hip/hip_runtime.h>

// Problem: N=8 prior blocks, B=4, C=256, H=W=64.
// V = concat(blocks, x) -> [9,4,256,64,64]
// GroupNorm(1 group) over (C,H,W) per (n,b); logits = <w, K> over c;
// softmax over n; out = sum_n attn * V.
//
// Key identity: logits = rstd*(S - mean*sum_wg) + sum_wgb
//   where S[n,b,hw] = sum_c (w[c]*gnw[c]) * V[n,b,c,hw]
//
// Two passes over V:
//   k1: stats (sum,sumsq) partials + channel-dot partials S_part.
//   k2: block = (b, 256-hw segment, 16-c chunk). Prologue: reduce stats +
//       logits + softmax for the segment. Main loop: wave streams
//       1KB-contiguous (n,c) rows.
// Lessons: r4: 32B strips -> exact 2x over-fetch. r5: 64B granules at
// 16KB stride -> 3.3 TB/s; need >=1KB contiguous per wave (6.4 TB/s).
// r7: parallelize prologue stat-reduce; preload first V planes into
// registers so the HBM stream starts during the prologue.

#define NPRI 8
#define N1   9
#define BB   4
#define CC   256
#define HWN  4096
#define CHW  (CC * HWN)          // 1048576
#define NB   (N1 * BB)           // 36
#define GN_EPS 1e-5f

// workspace layout (floats):
//   [0..2303]      psum[36][64]
//   [2304..4607]   psq [36][64]
//   [4608..)       S_part[4][36][4096] = 589824 floats
#define WS_PSUM   0
#define WS_PSQ    2304
#define WS_SPART  4608

// ---------------- kernel 1: stats + channel-dot partials ----------------
// grid = 36 (nb) * 4 (cq) * 16 (hwseg) = 2304 blocks (9 per CU),
// 256 threads = 4 c-groups (16 ch each) x 64 lanes (64 float4 = 256 floats).
__global__ __launch_bounds__(256, 4) void k1_stats(
        const float* __restrict__ blocks, const float* __restrict__ x,
        const float* __restrict__ w, const float* __restrict__ gnw,
        float* __restrict__ ws) {
    const int bid   = blockIdx.x;
    const int nb    = bid >> 6;          // 0..35
    const int rem   = bid & 63;
    const int cq    = rem >> 4;          // 0..3
    const int hwseg = rem & 15;          // 0..15
    const int t     = threadIdx.x;
    const int cg    = t >> 6;            // 0..3
    const int lane  = t & 63;

    const float* base = (nb < NPRI * BB)
        ? blocks + (size_t)nb * CHW
        : x + (size_t)(nb - NPRI * BB) * CHW;

    const int hw0 = hwseg * 256 + lane * 4;
    const int c0  = cq * 64 + cg * 16;

    float s0 = 0.f, s1 = 0.f, s2 = 0.f, s3 = 0.f;   // channel-dot partial
    float sum = 0.f, sq = 0.f;

    #pragma unroll 4
    for (int c = c0; c < c0 + 16; ++c) {
        const float4 v = *reinterpret_cast<const float4*>(base + (size_t)c * HWN + hw0);
        const float wg = w[c] * gnw[c];
        sum += v.x + v.y + v.z + v.w;
        sq  += v.x * v.x + v.y * v.y + v.z * v.z + v.w * v.w;
        s0 += wg * v.x; s1 += wg * v.y; s2 += wg * v.z; s3 += wg * v.w;
    }

    // combine 4 c-groups' channel-dot via LDS; cg0 writes final cq-partial
    __shared__ float4 sbuf[3][64];
    if (cg) sbuf[cg - 1][lane] = make_float4(s0, s1, s2, s3);
    __syncthreads();
    if (!cg) {
        #pragma unroll
        for (int g = 0; g < 3; ++g) {
            const float4 o = sbuf[g][lane];
            s0 += o.x; s1 += o.y; s2 += o.z; s3 += o.w;
        }
        float* Sp = ws + WS_SPART;
        *reinterpret_cast<float4*>(Sp + (size_t)(cq * NB + nb) * HWN + hw0) =
            make_float4(s0, s1, s2, s3);
    }

    // block-reduce sum/sq -> unique slot (no atomics)
    #pragma unroll
    for (int off = 32; off; off >>= 1) {
        sum += __shfl_down(sum, off);
        sq  += __shfl_down(sq, off);
    }
    __shared__ float red[8];
    if (lane == 0) { red[cg] = sum; red[4 + cg] = sq; }
    __syncthreads();
    if (t == 0) {
        const int slot = nb * 64 + rem;
        ws[WS_PSUM + slot] = red[0] + red[1] + red[2] + red[3];
        ws[WS_PSQ  + slot] = red[4] + red[5] + red[6] + red[7];
    }
}

// -------- kernel 2: fused stats-finalize + softmax + weighted sum --------
// grid = 4 (b) * 16 (hwseg of 256 hw) * 16 (c-chunk of 16) = 1024 blocks
// (4 per CU, one generation), 256 threads = 4 waves.
__global__ __launch_bounds__(256, 4) void k2_fused(
        const float* __restrict__ blocks, const float* __restrict__ x,
        const float* __restrict__ w, const float* __restrict__ gnw,
        const float* __restrict__ gnb,
        const float* __restrict__ ws, float* __restrict__ out) {
    const int bid   = blockIdx.x;
    const int b     = bid >> 8;          // 0..3
    const int hwseg = (bid >> 4) & 15;   // 0..15
    const int cch   = bid & 15;          // 0..15
    const int t     = threadIdx.x;
    const int wv    = t >> 6, lane = t & 63;

    const int hwbase = hwseg * 256;
    const int c0 = cch * 16;
    const int hw = hwbase + lane * 4;

    // ---- preload first 3 n-planes of V (issued before prologue; the
    // global loads complete while the prologue's L2 reads run) ----
    float4 pre[3][4];
    #pragma unroll
    for (int n = 0; n < 3; ++n) {
        const float* vb = blocks + (size_t)(n * BB + b) * CHW;  // n<3 < NPRI
        #pragma unroll
        for (int k = 0; k < 4; ++k)
            pre[n][k] = *reinterpret_cast<const float4*>(
                vb + (size_t)(c0 + wv + 4 * k) * HWN + hw);
    }

    __shared__ float red[8];
    __shared__ float swg_s, swgb_s;
    __shared__ float pred_s[NB][4], pred_q[NB][4];
    __shared__ float mean_s[NB], rstd_s[NB];
    __shared__ float attn_s[N1][256];    // logits, then attn (in place)

    // ---- swg = <w,gnw>, swgb = <w,gnb> (block reduce, C==256) ----
    {
        float p = w[t] * gnw[t];
        float q = w[t] * gnb[t];
        #pragma unroll
        for (int off = 32; off; off >>= 1) {
            p += __shfl_down(p, off);
            q += __shfl_down(q, off);
        }
        if (lane == 0) { red[wv] = p; red[4 + wv] = q; }
    }

    // ---- stats: 144 threads, each reduces 16 partials (4 per nb) ----
    if (t < NB * 4) {
        const int nb = t >> 2, j = t & 3;
        float s = 0.f, ss = 0.f;
        #pragma unroll 8
        for (int i = j * 16; i < j * 16 + 16; ++i) {
            s  += ws[WS_PSUM + nb * 64 + i];
            ss += ws[WS_PSQ  + nb * 64 + i];
        }
        pred_s[nb][j] = s;
        pred_q[nb][j] = ss;
    }
    __syncthreads();
    if (t < NB) {
        const float s  = pred_s[t][0] + pred_s[t][1] + pred_s[t][2] + pred_s[t][3];
        const float ss = pred_q[t][0] + pred_q[t][1] + pred_q[t][2] + pred_q[t][3];
        const float mean = s * (1.0f / CHW);
        const float var  = ss * (1.0f / CHW) - mean * mean;
        mean_s[t] = mean;
        rstd_s[t] = rsqrtf(var + GN_EPS);
    }
    if (t == 0) {
        swg_s  = red[0] + red[1] + red[2] + red[3];
        swgb_s = red[4] + red[5] + red[6] + red[7];
    }
    __syncthreads();

    // ---- logits for this 256-hw segment, all 9 n (coalesced 1KB rows) ----
    {
        const float* Sp = ws + WS_SPART;
        const float swg = swg_s, swgb = swgb_s;
        #pragma unroll
        for (int n = 0; n < N1; ++n) {
            const int nb = n * BB + b;
            const size_t o = (size_t)nb * HWN + hwbase + t;
            const float S = Sp[o] + Sp[(size_t)NB * HWN + o]
                          + Sp[(size_t)2 * NB * HWN + o] + Sp[(size_t)3 * NB * HWN + o];
            attn_s[n][t] = rstd_s[nb] * (S - mean_s[nb] * swg) + swgb;
        }
    }
    __syncthreads();

    // ---- softmax over n, thread t owns hw column t, in place ----
    {
        float l[N1];
        float mx = -1e30f;
        #pragma unroll
        for (int n = 0; n < N1; ++n) { l[n] = attn_s[n][t]; mx = fmaxf(mx, l[n]); }
        float den = 0.f;
        #pragma unroll
        for (int n = 0; n < N1; ++n) { l[n] = __expf(l[n] - mx); den += l[n]; }
        const float inv = 1.0f / den;
        #pragma unroll
        for (int n = 0; n < N1; ++n) attn_s[n][t] = l[n] * inv;
    }
    __syncthreads();

    // ---- weighted sum over n: wave wv streams (n, c) rows of 1KB ----
    float4 acc[4];
    #pragma unroll
    for (int k = 0; k < 4; ++k) acc[k] = make_float4(0.f, 0.f, 0.f, 0.f);

    // n = 0..2 from the preload registers
    #pragma unroll
    for (int n = 0; n < 3; ++n) {
        const float4 a = *reinterpret_cast<const float4*>(&attn_s[n][lane * 4]);
        #pragma unroll
        for (int k = 0; k < 4; ++k) {
            acc[k].x += a.x * pre[n][k].x; acc[k].y += a.y * pre[n][k].y;
            acc[k].z += a.z * pre[n][k].z; acc[k].w += a.w * pre[n][k].w;
        }
    }
    // n = 3..8 streamed
    #pragma unroll
    for (int n = 3; n < N1; ++n) {
        const float* vb = (n < NPRI)
            ? blocks + (size_t)(n * BB + b) * CHW
            : x + (size_t)b * CHW;
        const float4 a = *reinterpret_cast<const float4*>(&attn_s[n][lane * 4]);
        #pragma unroll
        for (int k = 0; k < 4; ++k) {
            const float4 v = *reinterpret_cast<const float4*>(
                vb + (size_t)(c0 + wv + 4 * k) * HWN + hw);
            acc[k].x += a.x * v.x; acc[k].y += a.y * v.y;
            acc[k].z += a.z * v.z; acc[k].w += a.w * v.w;
        }
    }

    #pragma unroll
    for (int k = 0; k < 4; ++k) {
        float* o = out + (size_t)(b * CC + c0 + wv + 4 * k) * HWN + hw;
        __builtin_nontemporal_store(acc[k].x, o + 0);
        __builtin_nontemporal_store(acc[k].y, o + 1);
        __builtin_nontemporal_store(acc[k].z, o + 2);
        __builtin_nontemporal_store(acc[k].w, o + 3);
    }
}

extern "C" void kernel_launch(void* const* d_in, const int* in_sizes, int n_in,
                              void* d_out, int out_size, void* d_ws, size_t ws_size,
                              hipStream_t stream) {
    const float* blocks = (const float*)d_in[0];
    const float* x      = (const float*)d_in[1];
    const float* w      = (const float*)d_in[2];
    const float* gnw    = (const float*)d_in[3];
    const float* gnb    = (const float*)d_in[4];
    float* out = (float*)d_out;
    float* ws  = (float*)d_ws;

    hipLaunchKernelGGL(k1_stats, dim3(2304), dim3(256), 0, stream, blocks, x, w, gnw, ws);
    hipLaunchKernelGGL(k2_fused, dim3(1024), dim3(256), 0, stream,
                       blocks, x, w, gnw, gnb, ws, out);
}